// Round 3
// baseline (726.719 us; speedup 1.0000x reference)
//
#include <hip/hip_runtime.h>

typedef __bf16 bf16_t;
typedef __bf16 bf16x8 __attribute__((ext_vector_type(8)));
typedef __bf16 bf16x4 __attribute__((ext_vector_type(4)));
typedef float  f32x4  __attribute__((ext_vector_type(4)));
typedef int    i32x4  __attribute__((ext_vector_type(4)));

#define B_      16
#define L_      2048
#define D_      128
#define QT      8
#define PITCH   2056            // bf16 elems per LDS score row
#define NEGINF  (-1.0e9f)
#define SCALE   0.08838834764831845f   // 1/sqrt(128)

// ---------------------------------------------------------------------------
// Kernel A: pack mask (int32 -> 1 bit) into each q-tile's attn output region;
//           optionally convert K fp32 -> bf16 into workspace.
// One wave per mask row. Bit layout (unchanged): in a tile region, byte
// [rr*256 + bc] covers cols bc*8..bc*8+7, bit u = col bc*8+u.
// ---------------------------------------------------------------------------
__global__ __launch_bounds__(256) void pack_mask_kernel(
    const int* __restrict__ mask, float* __restrict__ attn,
    const float* __restrict__ k, bf16_t* __restrict__ kb, int has_kb)
{
    const int tid  = threadIdx.x;
    const int l    = tid & 63;
    const int wrow = blockIdx.x * 4 + (tid >> 6);   // 0..32767
    const int b    = wrow >> 11;
    const int r    = wrow & 2047;
    const int qt   = r >> 3;                        // q-tile (QT=8)
    const int rr   = r & 7;

    const int* src = mask + ((size_t)b * L_ + r) * (size_t)L_;
    char* region = (char*)(attn + ((size_t)b * L_ + (size_t)qt * QT) * (size_t)L_);

    #pragma unroll
    for (int it = 0; it < 4; ++it) {
        const int c0 = it * 512 + l * 8;
        i32x4 v0 = __builtin_nontemporal_load((const i32x4*)(src + c0));
        i32x4 v1 = __builtin_nontemporal_load((const i32x4*)(src + c0 + 4));
        unsigned by = (v0[0] != 0 ? 1u : 0u)
                    | (v0[1] != 0 ? 2u : 0u)
                    | (v0[2] != 0 ? 4u : 0u)
                    | (v0[3] != 0 ? 8u : 0u)
                    | (v1[0] != 0 ? 16u : 0u)
                    | (v1[1] != 0 ? 32u : 0u)
                    | (v1[2] != 0 ? 64u : 0u)
                    | (v1[3] != 0 ? 128u : 0u);
        region[(size_t)rr * 256 + it * 64 + l] = (char)by;
    }

    if (has_kb) {
        const int idx = blockIdx.x * 256 + tid;
        const int nchunks = (B_ * L_ * D_) / 4;     // 1,048,576
        if (idx < nchunks) {
            f32x4 x = *(const f32x4*)(k + (size_t)idx * 4);
            bf16x4 o;
            #pragma unroll
            for (int i = 0; i < 4; ++i) o[i] = (bf16_t)x[i];
            *(bf16x4*)(kb + (size_t)idx * 4) = o;
        }
    }
}

// ---------------------------------------------------------------------------
// Kernel B: V fp32 [B][L][D] -> bf16 VT [B][D][L] (LDS-tiled transpose)
// ---------------------------------------------------------------------------
__global__ __launch_bounds__(256) void vt_kernel(
    const float* __restrict__ v, bf16_t* __restrict__ vt)
{
    __shared__ bf16_t tile[128 * 144];
    const int tid = threadIdx.x;
    const int b   = blockIdx.x >> 4;
    const int l0  = (blockIdx.x & 15) * 128;

    #pragma unroll
    for (int it = 0; it < 16; ++it) {
        int idx = tid + it * 256;
        int row = idx >> 5;
        int dc4 = idx & 31;
        f32x4 x = *(const f32x4*)(v + ((size_t)b * L_ + l0 + row) * (size_t)D_ + dc4 * 4);
        #pragma unroll
        for (int i = 0; i < 4; ++i) tile[(dc4 * 4 + i) * 144 + row] = (bf16_t)x[i];
    }
    __syncthreads();
    #pragma unroll
    for (int it = 0; it < 8; ++it) {
        int idx = tid + it * 256;
        int d   = idx >> 4;
        int lc  = idx & 15;
        bf16x8 vec = *(const bf16x8*)&tile[d * 144 + lc * 8];
        *(bf16x8*)(vt + ((size_t)b * D_ + d) * (size_t)L_ + l0 + lc * 8) = vec;
    }
}

// ---------------------------------------------------------------------------
// Main kernel: QT=8 rows per block, 33KB LDS -> 4 blocks/CU, 32 waves/CU.
// ---------------------------------------------------------------------------
__global__ __launch_bounds__(512, 8) void sdpa_kernel(
    const float* __restrict__ q, const float* __restrict__ k,
    const float* __restrict__ v,
    const bf16_t* __restrict__ kb, const bf16_t* __restrict__ vt,
    float* __restrict__ out, float* __restrict__ attn,
    int has_kb, int has_vt)
{
    __shared__ bf16_t sc[QT * PITCH];   // 32,896 B
    __shared__ float  inv_l[QT];

    const int tid = threadIdx.x;
    const int w   = tid >> 6;           // wave 0..7
    const int l   = tid & 63;
    const int li  = l & 15;
    const int lg  = l >> 4;
    const int q8  = li & 7;             // valid q row for this lane

    // XCD-chunked bijective swizzle (4096 % 8 == 0): 512 consecutive tiles per XCD
    const int bid  = (int)blockIdx.x;
    const int bid2 = (bid & 7) * 512 + (bid >> 3);
    const int b     = bid2 >> 8;        // 256 q-tiles per batch
    const int qtile = bid2 & 255;
    const int qbase = qtile * QT;

    const size_t bq = (size_t)b * L_;
    const float*  qp    = q   + (bq + qbase) * (size_t)D_;
    const float*  kp    = k   + bq * (size_t)D_;
    const float*  vp    = v   + bq * (size_t)D_;
    const bf16_t* kbp   = kb  + bq * (size_t)D_;
    const bf16_t* vtp   = vt  + (size_t)b * D_ * (size_t)L_;
    float*        outp  = out + (bq + qbase) * (size_t)D_;
    float*        attnp = attn + (bq + qbase) * (size_t)L_;

    // ---------------- Phase 0: Q B-fragments (pre-scaled), kept in regs
    bf16x8 aq[4];
    #pragma unroll
    for (int ds = 0; ds < 4; ++ds) {
        const float* p = qp + (size_t)q8 * D_ + ds * 32 + lg * 8;
        f32x4 x0 = *(const f32x4*)p;
        f32x4 x1 = *(const f32x4*)(p + 4);
        bf16x8 a;
        #pragma unroll
        for (int u = 0; u < 4; ++u) {
            a[u]     = (bf16_t)(x0[u] * SCALE);
            a[4 + u] = (bf16_t)(x1[u] * SCALE);
        }
        aq[ds] = a;
    }

    // ---------------- Phase 1: S^T tiles via mfma(K, Q); lanes li<8 store bf16x4
    if (has_kb) {
        bf16x8 KA[4], KB[4];
        auto loadKb = [&](int t, bf16x8* dst) {
            const bf16_t* p = kbp + (size_t)(w * 256 + t * 16 + li) * D_;
            #pragma unroll
            for (int ds = 0; ds < 4; ++ds) dst[ds] = *(const bf16x8*)(p + ds * 32 + lg * 8);
        };
        auto step = [&](int t, bf16x8* kf) {
            f32x4 acc = {0.f, 0.f, 0.f, 0.f};
            #pragma unroll
            for (int ds = 0; ds < 4; ++ds)
                acc = __builtin_amdgcn_mfma_f32_16x16x32_bf16(kf[ds], aq[ds], acc, 0, 0, 0);
            if (li < 8) {
                bf16x4 o;
                #pragma unroll
                for (int r = 0; r < 4; ++r) o[r] = (bf16_t)acc[r];
                *(bf16x4*)(sc + (size_t)li * PITCH + w * 256 + t * 16 + lg * 4) = o;
            }
        };
        loadKb(0, KA); loadKb(1, KB);
        #pragma unroll 1
        for (int t = 0; t < 16; t += 2) {
            step(t, KA);
            if (t + 2 < 16) loadKb(t + 2, KA);
            step(t + 1, KB);
            if (t + 3 < 16) loadKb(t + 3, KB);
        }
    } else {
        float kraw[32];
        auto loadKf = [&](int t, float* dst) {
            #pragma unroll
            for (int ds = 0; ds < 4; ++ds) {
                const float* p = kp + (size_t)(w * 256 + t * 16 + li) * D_ + ds * 32 + lg * 8;
                f32x4 x0 = *(const f32x4*)p;
                f32x4 x1 = *(const f32x4*)(p + 4);
                #pragma unroll
                for (int u = 0; u < 4; ++u) { dst[ds*8+u] = x0[u]; dst[ds*8+4+u] = x1[u]; }
            }
        };
        loadKf(0, kraw);
        #pragma unroll 1
        for (int t = 0; t < 16; ++t) {
            bf16x8 kf[4];
            #pragma unroll
            for (int ds = 0; ds < 4; ++ds) {
                bf16x8 a;
                #pragma unroll
                for (int u = 0; u < 8; ++u) a[u] = (bf16_t)kraw[ds*8+u];
                kf[ds] = a;
            }
            if (t + 1 < 16) loadKf(t + 1, kraw);
            f32x4 acc = {0.f, 0.f, 0.f, 0.f};
            #pragma unroll
            for (int ds = 0; ds < 4; ++ds)
                acc = __builtin_amdgcn_mfma_f32_16x16x32_bf16(kf[ds], aq[ds], acc, 0, 0, 0);
            if (li < 8) {
                bf16x4 o;
                #pragma unroll
                for (int r = 0; r < 4; ++r) o[r] = (bf16_t)acc[r];
                *(bf16x4*)(sc + (size_t)li * PITCH + w * 256 + t * 16 + lg * 4) = o;
            }
        }
    }
    __syncthreads();

    // ---------------- Phase 2: masked exact softmax; one wave per row
    {
        const int row = w;              // 8 rows, 8 waves
        const int c   = l;              // 64 threads per row
        bf16_t* srow = sc + (size_t)row * PITCH;
        const unsigned char* mb = (const unsigned char*)attnp + (size_t)row * 256;

        unsigned int mby[4];
        #pragma unroll
        for (int j = 0; j < 4; ++j) mby[j] = mb[c + j * 64];

        float m = -3.4e38f;
        #pragma unroll
        for (int j = 0; j < 4; ++j) {
            bf16x8 x = *(const bf16x8*)(srow + (c + j * 64) * 8);
            unsigned int bits = mby[j];
            #pragma unroll
            for (int u = 0; u < 8; ++u) {
                float s = (float)x[u] + (((bits >> u) & 1u) ? 0.f : NEGINF);
                m = fmaxf(m, s);
            }
        }
        #pragma unroll
        for (int off = 32; off; off >>= 1) m = fmaxf(m, __shfl_xor(m, off));

        float sum = 0.f;
        #pragma unroll
        for (int j = 0; j < 4; ++j) {
            bf16x8 x = *(bf16x8*)(srow + (c + j * 64) * 8);
            unsigned int bits = mby[j];
            bf16x8 e;
            #pragma unroll
            for (int u = 0; u < 8; ++u) {
                float s  = (float)x[u] + (((bits >> u) & 1u) ? 0.f : NEGINF);
                float ev = __expf(s - m);
                sum += ev;
                e[u] = (bf16_t)ev;
            }
            *(bf16x8*)(srow + (c + j * 64) * 8) = e;
        }
        #pragma unroll
        for (int off = 32; off; off >>= 1) sum += __shfl_xor(sum, off);
        if (c == 0) inv_l[row] = 1.f / sum;
    }
    __syncthreads();

    // ---------------- Phase 3 prologue: issue first V loads before the attn write
    const int d0 = w * 16;
    f32x4 acc3 = {0.f, 0.f, 0.f, 0.f};
    bf16x8 VB0, VB1, VB2, VB3;
    float vr0[8], vr1[8];
    auto loadVT = [&](int ks, bf16x8& dst) {
        dst = *(const bf16x8*)(vtp + (size_t)(d0 + li) * L_ + ks * 32 + lg * 8);
    };
    auto loadVg = [&](int ks, float* dst) {
        const float* p = vp + (size_t)(ks * 32 + lg * 8) * D_ + d0 + li;
        #pragma unroll
        for (int u = 0; u < 8; ++u) dst[u] = p[(size_t)u * D_];
    };
    if (has_vt) { loadVT(0, VB0); loadVT(1, VB1); loadVT(2, VB2); loadVT(3, VB3); }
    else        { loadVg(0, vr0); loadVg(1, vr1); }

    // ---------------- Phase 2b: write normalized attn (non-temporal f32x4)
    {
        #pragma unroll 1
        for (int i = 0; i < 8; ++i) {
            int f  = tid + i * 512;     // float4 index over 8x512
            int rw = f >> 9;
            int c4 = f & 511;
            bf16x4 x = *(const bf16x4*)(sc + (size_t)rw * PITCH + c4 * 4);
            float il = inv_l[rw];
            f32x4 o;
            o[0] = (float)x[0] * il; o[1] = (float)x[1] * il;
            o[2] = (float)x[2] * il; o[3] = (float)x[3] * il;
            __builtin_nontemporal_store(o, (f32x4*)(attnp + (size_t)rw * L_ + c4 * 4));
        }
    }

    // ---------------- Phase 3: out = (P·V) * inv_l
    if (has_vt) {
        #pragma unroll 1
        for (int ks = 0; ks < 64; ks += 4) {
            bf16x8 a0 = *(const bf16x8*)(sc + (size_t)q8 * PITCH + ks * 32 + lg * 8);
            acc3 = __builtin_amdgcn_mfma_f32_16x16x32_bf16(a0, VB0, acc3, 0, 0, 0);
            if (ks + 4 < 64) loadVT(ks + 4, VB0);
            bf16x8 a1 = *(const bf16x8*)(sc + (size_t)q8 * PITCH + (ks + 1) * 32 + lg * 8);
            acc3 = __builtin_amdgcn_mfma_f32_16x16x32_bf16(a1, VB1, acc3, 0, 0, 0);
            if (ks + 5 < 64) loadVT(ks + 5, VB1);
            bf16x8 a2 = *(const bf16x8*)(sc + (size_t)q8 * PITCH + (ks + 2) * 32 + lg * 8);
            acc3 = __builtin_amdgcn_mfma_f32_16x16x32_bf16(a2, VB2, acc3, 0, 0, 0);
            if (ks + 6 < 64) loadVT(ks + 6, VB2);
            bf16x8 a3 = *(const bf16x8*)(sc + (size_t)q8 * PITCH + (ks + 3) * 32 + lg * 8);
            acc3 = __builtin_amdgcn_mfma_f32_16x16x32_bf16(a3, VB3, acc3, 0, 0, 0);
            if (ks + 7 < 64) loadVT(ks + 7, VB3);
        }
    } else {
        #pragma unroll 1
        for (int ks = 0; ks < 64; ks += 2) {
            bf16x8 bb;
            #pragma unroll
            for (int u = 0; u < 8; ++u) bb[u] = (bf16_t)vr0[u];
            if (ks + 2 < 64) loadVg(ks + 2, vr0);
            bf16x8 a0 = *(const bf16x8*)(sc + (size_t)q8 * PITCH + ks * 32 + lg * 8);
            acc3 = __builtin_amdgcn_mfma_f32_16x16x32_bf16(a0, bb, acc3, 0, 0, 0);

            bf16x8 bb1;
            #pragma unroll
            for (int u = 0; u < 8; ++u) bb1[u] = (bf16_t)vr1[u];
            if (ks + 3 < 64) loadVg(ks + 3, vr1);
            bf16x8 a1 = *(const bf16x8*)(sc + (size_t)q8 * PITCH + (ks + 1) * 32 + lg * 8);
            acc3 = __builtin_amdgcn_mfma_f32_16x16x32_bf16(a1, bb1, acc3, 0, 0, 0);
        }
    }

    {
        const int dcol = d0 + li;
        if (lg < 2) {
            #pragma unroll
            for (int r = 0; r < 4; ++r) {
                int row = lg * 4 + r;   // 0..7
                outp[(size_t)row * D_ + dcol] = acc3[r] * inv_l[row];
            }
        }
    }
}

extern "C" void kernel_launch(void* const* d_in, const int* in_sizes, int n_in,
                              void* d_out, int out_size, void* d_ws, size_t ws_size,
                              hipStream_t stream) {
    const float* q    = (const float*)d_in[0];
    const float* k    = (const float*)d_in[1];
    const float* v    = (const float*)d_in[2];
    const int*   mask = (const int*)d_in[3];

    float* out  = (float*)d_out;
    float* attn = out + (size_t)B_ * L_ * D_;

    const size_t VT_BYTES = (size_t)B_ * D_ * L_ * 2;   // 8 MB
    const size_t KB_BYTES = (size_t)B_ * L_ * D_ * 2;   // 8 MB
    const int has_vt = ws_size >= VT_BYTES ? 1 : 0;
    const int has_kb = ws_size >= VT_BYTES + KB_BYTES ? 1 : 0;
    bf16_t* vt = (bf16_t*)d_ws;
    bf16_t* kb = (bf16_t*)((char*)d_ws + VT_BYTES);

    hipLaunchKernelGGL(pack_mask_kernel, dim3(8192), dim3(256), 0, stream,
                       mask, attn, k, kb, has_kb);
    if (has_vt)
        hipLaunchKernelGGL(vt_kernel, dim3(256), dim3(256), 0, stream, v, vt);
    hipLaunchKernelGGL(sdpa_kernel, dim3(4096), dim3(512), 0, stream,
                       q, k, v, kb, vt, out, attn, has_kb, has_vt);
}

// Round 4
// 627.841 us; speedup vs baseline: 1.1575x; 1.1575x over previous
//
#include <hip/hip_runtime.h>

typedef __bf16 bf16_t;
typedef __bf16 bf16x8 __attribute__((ext_vector_type(8)));
typedef __bf16 bf16x4 __attribute__((ext_vector_type(4)));
typedef float  f32x4  __attribute__((ext_vector_type(4)));
typedef int    i32x4  __attribute__((ext_vector_type(4)));

#define B_      16
#define L_      2048
#define D_      128
#define QT      8
#define PITCH   2056            // bf16 elems per LDS score row
#define NEGINF  (-1.0e9f)
#define SCALE   0.08838834764831845f   // 1/sqrt(128)

// ---------------------------------------------------------------------------
// Kernel A: pack mask (int32 -> 1 bit) into each q-tile's attn output region;
//           optionally convert K fp32 -> bf16 into workspace.
// One wave per mask row. Bit layout: in a tile region, byte [rr*256 + bc]
// covers cols bc*8..bc*8+7, bit u = col bc*8+u.
// ---------------------------------------------------------------------------
__global__ __launch_bounds__(256) void pack_mask_kernel(
    const int* __restrict__ mask, float* __restrict__ attn,
    const float* __restrict__ k, bf16_t* __restrict__ kb, int has_kb)
{
    const int tid  = threadIdx.x;
    const int l    = tid & 63;
    const int wrow = blockIdx.x * 4 + (tid >> 6);   // 0..32767
    const int b    = wrow >> 11;
    const int r    = wrow & 2047;
    const int qt   = r >> 3;                        // q-tile (QT=8)
    const int rr   = r & 7;

    const int* src = mask + ((size_t)b * L_ + r) * (size_t)L_;
    char* region = (char*)(attn + ((size_t)b * L_ + (size_t)qt * QT) * (size_t)L_);

    #pragma unroll
    for (int it = 0; it < 4; ++it) {
        const int c0 = it * 512 + l * 8;
        i32x4 v0 = __builtin_nontemporal_load((const i32x4*)(src + c0));
        i32x4 v1 = __builtin_nontemporal_load((const i32x4*)(src + c0 + 4));
        unsigned by = (v0[0] != 0 ? 1u : 0u)
                    | (v0[1] != 0 ? 2u : 0u)
                    | (v0[2] != 0 ? 4u : 0u)
                    | (v0[3] != 0 ? 8u : 0u)
                    | (v1[0] != 0 ? 16u : 0u)
                    | (v1[1] != 0 ? 32u : 0u)
                    | (v1[2] != 0 ? 64u : 0u)
                    | (v1[3] != 0 ? 128u : 0u);
        region[(size_t)rr * 256 + it * 64 + l] = (char)by;
    }

    if (has_kb) {
        const int idx = blockIdx.x * 256 + tid;
        const int nchunks = (B_ * L_ * D_) / 4;     // 1,048,576
        if (idx < nchunks) {
            f32x4 x = __builtin_nontemporal_load((const f32x4*)(k + (size_t)idx * 4));
            bf16x4 o;
            #pragma unroll
            for (int i = 0; i < 4; ++i) o[i] = (bf16_t)x[i];
            *(bf16x4*)(kb + (size_t)idx * 4) = o;
        }
    }
}

// ---------------------------------------------------------------------------
// Kernel B: V fp32 [B][L][D] -> bf16 VT [B][D][L] (LDS-tiled transpose)
// ---------------------------------------------------------------------------
__global__ __launch_bounds__(256) void vt_kernel(
    const float* __restrict__ v, bf16_t* __restrict__ vt)
{
    __shared__ bf16_t tile[128 * 144];
    const int tid = threadIdx.x;
    const int b   = blockIdx.x >> 4;
    const int l0  = (blockIdx.x & 15) * 128;

    #pragma unroll
    for (int it = 0; it < 16; ++it) {
        int idx = tid + it * 256;
        int row = idx >> 5;
        int dc4 = idx & 31;
        f32x4 x = __builtin_nontemporal_load(
            (const f32x4*)(v + ((size_t)b * L_ + l0 + row) * (size_t)D_ + dc4 * 4));
        #pragma unroll
        for (int i = 0; i < 4; ++i) tile[(dc4 * 4 + i) * 144 + row] = (bf16_t)x[i];
    }
    __syncthreads();
    #pragma unroll
    for (int it = 0; it < 8; ++it) {
        int idx = tid + it * 256;
        int d   = idx >> 4;
        int lc  = idx & 15;
        bf16x8 vec = *(const bf16x8*)&tile[d * 144 + lc * 8];
        *(bf16x8*)(vt + ((size_t)b * D_ + d) * (size_t)L_ + l0 + lc * 8) = vec;
    }
}

// ---------------------------------------------------------------------------
// Main kernel: QT=8 rows per block, 33KB LDS, launch_bounds(512,6):
// VGPR cap ~85 (no spill), 3 blocks/CU, 24 waves/CU.
// ---------------------------------------------------------------------------
__global__ __launch_bounds__(512, 6) void sdpa_kernel(
    const float* __restrict__ q, const float* __restrict__ k,
    const float* __restrict__ v,
    const bf16_t* __restrict__ kb, const bf16_t* __restrict__ vt,
    float* __restrict__ out, float* __restrict__ attn,
    int has_kb, int has_vt)
{
    __shared__ bf16_t sc[QT * PITCH];   // 32,896 B
    __shared__ float  inv_l[QT];

    const int tid = threadIdx.x;
    const int w   = tid >> 6;           // wave 0..7
    const int l   = tid & 63;
    const int li  = l & 15;
    const int lg  = l >> 4;
    const int q8  = li & 7;             // valid q row for this lane

    // XCD-chunked bijective swizzle (4096 % 8 == 0)
    const int bid  = (int)blockIdx.x;
    const int bid2 = (bid & 7) * 512 + (bid >> 3);
    const int b     = bid2 >> 8;        // 256 q-tiles per batch
    const int qtile = bid2 & 255;
    const int qbase = qtile * QT;

    const size_t bq = (size_t)b * L_;
    const float*  qp    = q   + (bq + qbase) * (size_t)D_;
    const float*  kp    = k   + bq * (size_t)D_;
    const float*  vp    = v   + bq * (size_t)D_;
    const bf16_t* kbp   = kb  + bq * (size_t)D_;
    const bf16_t* vtp   = vt  + (size_t)b * D_ * (size_t)L_;
    float*        outp  = out + (bq + qbase) * (size_t)D_;
    float*        attnp = attn + (bq + qbase) * (size_t)L_;

    // ---------------- Mask byte prefetch (consumed in softmax; latency hidden
    // under phase 1). Softmax assignment: row = w, col chunk = l + j*64.
    unsigned int mby[4];
    {
        const unsigned char* mb = (const unsigned char*)attnp + (size_t)w * 256;
        #pragma unroll
        for (int j = 0; j < 4; ++j) mby[j] = mb[l + j * 64];
    }

    // ---------------- Phase 0: Q B-fragments (pre-scaled), kept in regs
    bf16x8 aq[4];
    #pragma unroll
    for (int ds = 0; ds < 4; ++ds) {
        const float* p = qp + (size_t)q8 * D_ + ds * 32 + lg * 8;
        f32x4 x0 = *(const f32x4*)p;
        f32x4 x1 = *(const f32x4*)(p + 4);
        bf16x8 a;
        #pragma unroll
        for (int u = 0; u < 4; ++u) {
            a[u]     = (bf16_t)(x0[u] * SCALE);
            a[4 + u] = (bf16_t)(x1[u] * SCALE);
        }
        aq[ds] = a;
    }

    // ---------------- Phase 1: S^T tiles via mfma(K, Q); lanes li<8 store bf16x4
    if (has_kb) {
        bf16x8 KA[4], KB[4];
        auto loadKb = [&](int t, bf16x8* dst) {
            const bf16_t* p = kbp + (size_t)(w * 256 + t * 16 + li) * D_;
            #pragma unroll
            for (int ds = 0; ds < 4; ++ds) dst[ds] = *(const bf16x8*)(p + ds * 32 + lg * 8);
        };
        auto step = [&](int t, bf16x8* kf) {
            f32x4 acc = {0.f, 0.f, 0.f, 0.f};
            #pragma unroll
            for (int ds = 0; ds < 4; ++ds)
                acc = __builtin_amdgcn_mfma_f32_16x16x32_bf16(kf[ds], aq[ds], acc, 0, 0, 0);
            if (li < 8) {
                bf16x4 o;
                #pragma unroll
                for (int r = 0; r < 4; ++r) o[r] = (bf16_t)acc[r];
                *(bf16x4*)(sc + (size_t)li * PITCH + w * 256 + t * 16 + lg * 4) = o;
            }
        };
        loadKb(0, KA); loadKb(1, KB);
        #pragma unroll 1
        for (int t = 0; t < 16; t += 2) {
            step(t, KA);
            if (t + 2 < 16) loadKb(t + 2, KA);
            step(t + 1, KB);
            if (t + 3 < 16) loadKb(t + 3, KB);
        }
    } else {
        float kraw[32];
        auto loadKf = [&](int t, float* dst) {
            #pragma unroll
            for (int ds = 0; ds < 4; ++ds) {
                const float* p = kp + (size_t)(w * 256 + t * 16 + li) * D_ + ds * 32 + lg * 8;
                f32x4 x0 = *(const f32x4*)p;
                f32x4 x1 = *(const f32x4*)(p + 4);
                #pragma unroll
                for (int u = 0; u < 4; ++u) { dst[ds*8+u] = x0[u]; dst[ds*8+4+u] = x1[u]; }
            }
        };
        loadKf(0, kraw);
        #pragma unroll 1
        for (int t = 0; t < 16; ++t) {
            bf16x8 kf[4];
            #pragma unroll
            for (int ds = 0; ds < 4; ++ds) {
                bf16x8 a;
                #pragma unroll
                for (int u = 0; u < 8; ++u) a[u] = (bf16_t)kraw[ds*8+u];
                kf[ds] = a;
            }
            if (t + 1 < 16) loadKf(t + 1, kraw);
            f32x4 acc = {0.f, 0.f, 0.f, 0.f};
            #pragma unroll
            for (int ds = 0; ds < 4; ++ds)
                acc = __builtin_amdgcn_mfma_f32_16x16x32_bf16(kf[ds], aq[ds], acc, 0, 0, 0);
            if (li < 8) {
                bf16x4 o;
                #pragma unroll
                for (int r = 0; r < 4; ++r) o[r] = (bf16_t)acc[r];
                *(bf16x4*)(sc + (size_t)li * PITCH + w * 256 + t * 16 + lg * 4) = o;
            }
        }
    }
    __syncthreads();

    // ---------------- Phase 3 prologue: issue first V loads (hidden under softmax)
    const int d0 = w * 16;
    f32x4 acc3 = {0.f, 0.f, 0.f, 0.f};
    bf16x8 VB0, VB1, VB2, VB3;
    float vr0[8], vr1[8];
    auto loadVT = [&](int ks, bf16x8& dst) {
        dst = *(const bf16x8*)(vtp + (size_t)(d0 + li) * L_ + ks * 32 + lg * 8);
    };
    auto loadVg = [&](int ks, float* dst) {
        const float* p = vp + (size_t)(ks * 32 + lg * 8) * D_ + d0 + li;
        #pragma unroll
        for (int u = 0; u < 8; ++u) dst[u] = p[(size_t)u * D_];
    };
    if (has_vt) { loadVT(0, VB0); loadVT(1, VB1); loadVT(2, VB2); loadVT(3, VB3); }
    else        { loadVg(0, vr0); loadVg(1, vr1); }

    // ---------------- Phase 2: masked exact softmax; one wave per row
    {
        const int row = w;              // 8 rows, 8 waves
        const int c   = l;              // 64 threads per row
        bf16_t* srow = sc + (size_t)row * PITCH;

        float m = -3.4e38f;
        #pragma unroll
        for (int j = 0; j < 4; ++j) {
            bf16x8 x = *(const bf16x8*)(srow + (c + j * 64) * 8);
            unsigned int bits = mby[j];
            #pragma unroll
            for (int u = 0; u < 8; ++u) {
                float s = (float)x[u] + (((bits >> u) & 1u) ? 0.f : NEGINF);
                m = fmaxf(m, s);
            }
        }
        #pragma unroll
        for (int off = 32; off; off >>= 1) m = fmaxf(m, __shfl_xor(m, off));

        float sum = 0.f;
        #pragma unroll
        for (int j = 0; j < 4; ++j) {
            bf16x8 x = *(bf16x8*)(srow + (c + j * 64) * 8);
            unsigned int bits = mby[j];
            bf16x8 e;
            #pragma unroll
            for (int u = 0; u < 8; ++u) {
                float s  = (float)x[u] + (((bits >> u) & 1u) ? 0.f : NEGINF);
                float ev = __expf(s - m);
                sum += ev;
                e[u] = (bf16_t)ev;
            }
            *(bf16x8*)(srow + (c + j * 64) * 8) = e;
        }
        #pragma unroll
        for (int off = 32; off; off >>= 1) sum += __shfl_xor(sum, off);
        if (c == 0) inv_l[row] = 1.f / sum;
    }
    __syncthreads();

    // ---------------- Phase 3: fused PV MFMA + attn write.
    // Chunk ks (32 k-cols) is written by wave (ks & 7): one ds_read_b64 +
    // one non-temporal f32x4 store per owned iteration, spread evenly.
    const float il8 = inv_l[l >> 3];    // attn-write row for this lane
    const int   wrow_ = l >> 3;
    const int   wc4_  = (l & 7) * 4;

    if (has_vt) {
        auto pvstep = [&](int ks, bf16x8& VB) {
            bf16x8 a0 = *(const bf16x8*)(sc + (size_t)q8 * PITCH + ks * 32 + lg * 8);
            acc3 = __builtin_amdgcn_mfma_f32_16x16x32_bf16(a0, VB, acc3, 0, 0, 0);
            if ((ks & 7) == w) {
                bf16x4 x = *(const bf16x4*)(sc + (size_t)wrow_ * PITCH + ks * 32 + wc4_);
                f32x4 o;
                o[0] = (float)x[0] * il8; o[1] = (float)x[1] * il8;
                o[2] = (float)x[2] * il8; o[3] = (float)x[3] * il8;
                __builtin_nontemporal_store(o, (f32x4*)(attnp + (size_t)wrow_ * L_ + ks * 32 + wc4_));
            }
        };
        #pragma unroll 1
        for (int ks = 0; ks < 64; ks += 4) {
            pvstep(ks, VB0);     if (ks + 4 < 64) loadVT(ks + 4, VB0);
            pvstep(ks + 1, VB1); if (ks + 5 < 64) loadVT(ks + 5, VB1);
            pvstep(ks + 2, VB2); if (ks + 6 < 64) loadVT(ks + 6, VB2);
            pvstep(ks + 3, VB3); if (ks + 7 < 64) loadVT(ks + 7, VB3);
        }
    } else {
        // Fallback: separate attn write, then PV with fp32 V gather
        #pragma unroll 1
        for (int i = 0; i < 8; ++i) {
            int f  = tid + i * 512;
            int rw = f >> 9;
            int c4 = f & 511;
            bf16x4 x = *(const bf16x4*)(sc + (size_t)rw * PITCH + c4 * 4);
            float il = inv_l[rw];
            f32x4 o;
            o[0] = (float)x[0] * il; o[1] = (float)x[1] * il;
            o[2] = (float)x[2] * il; o[3] = (float)x[3] * il;
            __builtin_nontemporal_store(o, (f32x4*)(attnp + (size_t)rw * L_ + c4 * 4));
        }
        #pragma unroll 1
        for (int ks = 0; ks < 64; ks += 2) {
            bf16x8 bb;
            #pragma unroll
            for (int u = 0; u < 8; ++u) bb[u] = (bf16_t)vr0[u];
            if (ks + 2 < 64) loadVg(ks + 2, vr0);
            bf16x8 a0 = *(const bf16x8*)(sc + (size_t)q8 * PITCH + ks * 32 + lg * 8);
            acc3 = __builtin_amdgcn_mfma_f32_16x16x32_bf16(a0, bb, acc3, 0, 0, 0);

            bf16x8 bb1;
            #pragma unroll
            for (int u = 0; u < 8; ++u) bb1[u] = (bf16_t)vr1[u];
            if (ks + 3 < 64) loadVg(ks + 3, vr1);
            bf16x8 a1 = *(const bf16x8*)(sc + (size_t)q8 * PITCH + (ks + 1) * 32 + lg * 8);
            acc3 = __builtin_amdgcn_mfma_f32_16x16x32_bf16(a1, bb1, acc3, 0, 0, 0);
        }
    }

    // ---------------- Epilogue: out = acc * inv_l
    {
        const int dcol = d0 + li;
        if (lg < 2) {
            #pragma unroll
            for (int r = 0; r < 4; ++r) {
                int row = lg * 4 + r;   // 0..7
                __builtin_nontemporal_store(acc3[r] * inv_l[row],
                                            outp + (size_t)row * D_ + dcol);
            }
        }
    }
}

extern "C" void kernel_launch(void* const* d_in, const int* in_sizes, int n_in,
                              void* d_out, int out_size, void* d_ws, size_t ws_size,
                              hipStream_t stream) {
    const float* q    = (const float*)d_in[0];
    const float* k    = (const float*)d_in[1];
    const float* v    = (const float*)d_in[2];
    const int*   mask = (const int*)d_in[3];

    float* out  = (float*)d_out;
    float* attn = out + (size_t)B_ * L_ * D_;

    const size_t VT_BYTES = (size_t)B_ * D_ * L_ * 2;   // 8 MB
    const size_t KB_BYTES = (size_t)B_ * L_ * D_ * 2;   // 8 MB
    const int has_vt = ws_size >= VT_BYTES ? 1 : 0;
    const int has_kb = ws_size >= VT_BYTES + KB_BYTES ? 1 : 0;
    bf16_t* vt = (bf16_t*)d_ws;
    bf16_t* kb = (bf16_t*)((char*)d_ws + VT_BYTES);

    hipLaunchKernelGGL(pack_mask_kernel, dim3(8192), dim3(256), 0, stream,
                       mask, attn, k, kb, has_kb);
    if (has_vt)
        hipLaunchKernelGGL(vt_kernel, dim3(256), dim3(256), 0, stream, v, vt);
    hipLaunchKernelGGL(sdpa_kernel, dim3(4096), dim3(512), 0, stream,
                       q, k, v, kb, vt, out, attn, has_kb, has_vt);
}

// Round 5
// 527.924 us; speedup vs baseline: 1.3766x; 1.1893x over previous
//
#include <hip/hip_runtime.h>

typedef __bf16 bf16_t;
typedef __bf16 bf16x8 __attribute__((ext_vector_type(8)));
typedef __bf16 bf16x4 __attribute__((ext_vector_type(4)));
typedef float  f32x4  __attribute__((ext_vector_type(4)));
typedef int    i32x4  __attribute__((ext_vector_type(4)));

#define B_      16
#define L_      2048
#define D_      128
#define QT      8
#define PITCH   2056            // bf16 elems per LDS score row
#define NEGINF  (-1.0e9f)
#define SCALE   0.08838834764831845f   // 1/sqrt(128)

// ---------------------------------------------------------------------------
// Prep kernel: blocks 0..255  : V fp32 [B][L][D] -> bf16 VT [B][D][L]
//              blocks 256..511: K fp32 -> bf16 (same layout)
// ---------------------------------------------------------------------------
__global__ __launch_bounds__(256) void prep_kernel(
    const float* __restrict__ k, const float* __restrict__ v,
    bf16_t* __restrict__ kb, bf16_t* __restrict__ vt)
{
    __shared__ bf16_t tile[128 * 144];
    const int tid = threadIdx.x;
    const int bid = (int)blockIdx.x;

    if (bid < 256) {
        const int b  = bid >> 4;
        const int l0 = (bid & 15) * 128;
        #pragma unroll
        for (int it = 0; it < 16; ++it) {
            int idx = tid + it * 256;
            int row = idx >> 5;
            int dc4 = idx & 31;
            f32x4 x = __builtin_nontemporal_load(
                (const f32x4*)(v + ((size_t)b * L_ + l0 + row) * (size_t)D_ + dc4 * 4));
            #pragma unroll
            for (int i = 0; i < 4; ++i) tile[(dc4 * 4 + i) * 144 + row] = (bf16_t)x[i];
        }
        __syncthreads();
        #pragma unroll
        for (int it = 0; it < 8; ++it) {
            int idx = tid + it * 256;
            int d   = idx >> 4;
            int lc  = idx & 15;
            bf16x8 vec = *(const bf16x8*)&tile[d * 144 + lc * 8];
            *(bf16x8*)(vt + ((size_t)b * D_ + d) * (size_t)L_ + l0 + lc * 8) = vec;
        }
    } else {
        const int idx0 = (bid - 256) * 256 + tid;   // 65536 threads, 1M chunks
        #pragma unroll
        for (int c = 0; c < 16; ++c) {
            int idx = idx0 + c * 65536;
            f32x4 x = __builtin_nontemporal_load((const f32x4*)(k + (size_t)idx * 4));
            bf16x4 o;
            #pragma unroll
            for (int i = 0; i < 4; ++i) o[i] = (bf16_t)x[i];
            *(bf16x4*)(kb + (size_t)idx * 4) = o;
        }
    }
}

// ---------------------------------------------------------------------------
// Main kernel: QT=8 rows/block, 33KB LDS, launch_bounds(512,4) -> VGPR cap 64,
// 4 blocks/CU, 32 waves/CU. Mask read inline (raw int32, NT streaming).
// WS=1: bf16 K + transposed bf16 V from workspace. WS=0: fp32 fallbacks.
// ---------------------------------------------------------------------------
template <bool WS>
__global__ __launch_bounds__(512, 4) void sdpa_kernel(
    const float* __restrict__ q, const float* __restrict__ k,
    const float* __restrict__ v, const int* __restrict__ mask,
    const bf16_t* __restrict__ kb, const bf16_t* __restrict__ vt,
    float* __restrict__ out, float* __restrict__ attn)
{
    __shared__ bf16_t sc[QT * PITCH];   // 32,896 B
    __shared__ float  inv_l[QT];

    const int tid = threadIdx.x;
    const int w   = tid >> 6;           // wave 0..7
    const int l   = tid & 63;
    const int li  = l & 15;
    const int lg  = l >> 4;
    const int q8  = li & 7;             // valid q row for this lane

    // XCD-chunked bijective swizzle (4096 % 8 == 0)
    const int bid  = (int)blockIdx.x;
    const int bid2 = (bid & 7) * 512 + (bid >> 3);
    const int b     = bid2 >> 8;        // 256 q-tiles per batch
    const int qtile = bid2 & 255;
    const int qbase = qtile * QT;

    const size_t bq = (size_t)b * L_;
    const float*  qp    = q   + (bq + qbase) * (size_t)D_;
    const float*  kp    = k   + bq * (size_t)D_;
    const float*  vp    = v   + bq * (size_t)D_;
    const bf16_t* kbp   = kb  + bq * (size_t)D_;
    const bf16_t* vtp   = vt  + (size_t)b * D_ * (size_t)L_;
    float*        outp  = out + (bq + qbase) * (size_t)D_;
    float*        attnp = attn + (bq + qbase) * (size_t)L_;

    // ---------------- Inline mask load (row = w), compressed to 32 bits/chunk.
    // Thread (w,l) needs mask cols [8l+512j, 8l+512j+8) -- exactly its softmax
    // chunk. NT i32x4 loads, latency hidden under phase 0/1 compute.
    unsigned int mby[4];
    {
        const int* mrow = mask + (bq + qbase + w) * (size_t)L_;
        #pragma unroll
        for (int j = 0; j < 4; ++j) {
            const int c0 = (l + j * 64) * 8;
            i32x4 v0 = __builtin_nontemporal_load((const i32x4*)(mrow + c0));
            i32x4 v1 = __builtin_nontemporal_load((const i32x4*)(mrow + c0 + 4));
            mby[j] = (v0[0] != 0 ? 1u : 0u)
                   | (v0[1] != 0 ? 2u : 0u)
                   | (v0[2] != 0 ? 4u : 0u)
                   | (v0[3] != 0 ? 8u : 0u)
                   | (v1[0] != 0 ? 16u : 0u)
                   | (v1[1] != 0 ? 32u : 0u)
                   | (v1[2] != 0 ? 64u : 0u)
                   | (v1[3] != 0 ? 128u : 0u);
        }
    }

    // ---------------- Phase 0: Q B-fragments (pre-scaled), kept in regs
    bf16x8 aq[4];
    #pragma unroll
    for (int ds = 0; ds < 4; ++ds) {
        const float* p = qp + (size_t)q8 * D_ + ds * 32 + lg * 8;
        f32x4 x0 = *(const f32x4*)p;
        f32x4 x1 = *(const f32x4*)(p + 4);
        bf16x8 a;
        #pragma unroll
        for (int u = 0; u < 4; ++u) {
            a[u]     = (bf16_t)(x0[u] * SCALE);
            a[4 + u] = (bf16_t)(x1[u] * SCALE);
        }
        aq[ds] = a;
    }

    // ---------------- Phase 1: S^T tiles via mfma(K, Q); lanes li<8 store bf16x4
    if (WS) {
        bf16x8 KA[4], KB[4];
        auto loadKb = [&](int t, bf16x8* dst) {
            const bf16_t* p = kbp + (size_t)(w * 256 + t * 16 + li) * D_;
            #pragma unroll
            for (int ds = 0; ds < 4; ++ds) dst[ds] = *(const bf16x8*)(p + ds * 32 + lg * 8);
        };
        auto step = [&](int t, bf16x8* kf) {
            f32x4 acc = {0.f, 0.f, 0.f, 0.f};
            #pragma unroll
            for (int ds = 0; ds < 4; ++ds)
                acc = __builtin_amdgcn_mfma_f32_16x16x32_bf16(kf[ds], aq[ds], acc, 0, 0, 0);
            if (li < 8) {
                bf16x4 o;
                #pragma unroll
                for (int r = 0; r < 4; ++r) o[r] = (bf16_t)acc[r];
                *(bf16x4*)(sc + (size_t)li * PITCH + w * 256 + t * 16 + lg * 4) = o;
            }
        };
        loadKb(0, KA); loadKb(1, KB);
        #pragma unroll 1
        for (int t = 0; t < 16; t += 2) {
            step(t, KA);
            if (t + 2 < 16) loadKb(t + 2, KA);
            step(t + 1, KB);
            if (t + 3 < 16) loadKb(t + 3, KB);
        }
    } else {
        float kraw[32];
        auto loadKf = [&](int t, float* dst) {
            #pragma unroll
            for (int ds = 0; ds < 4; ++ds) {
                const float* p = kp + (size_t)(w * 256 + t * 16 + li) * D_ + ds * 32 + lg * 8;
                f32x4 x0 = *(const f32x4*)p;
                f32x4 x1 = *(const f32x4*)(p + 4);
                #pragma unroll
                for (int u = 0; u < 4; ++u) { dst[ds*8+u] = x0[u]; dst[ds*8+4+u] = x1[u]; }
            }
        };
        loadKf(0, kraw);
        #pragma unroll 1
        for (int t = 0; t < 16; ++t) {
            bf16x8 kf[4];
            #pragma unroll
            for (int ds = 0; ds < 4; ++ds) {
                bf16x8 a;
                #pragma unroll
                for (int u = 0; u < 8; ++u) a[u] = (bf16_t)kraw[ds*8+u];
                kf[ds] = a;
            }
            if (t + 1 < 16) loadKf(t + 1, kraw);
            f32x4 acc = {0.f, 0.f, 0.f, 0.f};
            #pragma unroll
            for (int ds = 0; ds < 4; ++ds)
                acc = __builtin_amdgcn_mfma_f32_16x16x32_bf16(kf[ds], aq[ds], acc, 0, 0, 0);
            if (li < 8) {
                bf16x4 o;
                #pragma unroll
                for (int r = 0; r < 4; ++r) o[r] = (bf16_t)acc[r];
                *(bf16x4*)(sc + (size_t)li * PITCH + w * 256 + t * 16 + lg * 4) = o;
            }
        }
    }
    __syncthreads();

    // ---------------- Phase 3 prologue: issue first V loads (hidden under softmax)
    const int d0 = w * 16;
    f32x4 acc3 = {0.f, 0.f, 0.f, 0.f};
    bf16x8 VB0, VB1, VB2, VB3;
    float vr0[8], vr1[8];
    auto loadVT = [&](int ks, bf16x8& dst) {
        dst = *(const bf16x8*)(vtp + (size_t)(d0 + li) * L_ + ks * 32 + lg * 8);
    };
    auto loadVg = [&](int ks, float* dst) {
        const float* p = vp + (size_t)(ks * 32 + lg * 8) * D_ + d0 + li;
        #pragma unroll
        for (int u = 0; u < 8; ++u) dst[u] = p[(size_t)u * D_];
    };
    if (WS) { loadVT(0, VB0); loadVT(1, VB1); loadVT(2, VB2); loadVT(3, VB3); }
    else    { loadVg(0, vr0); loadVg(1, vr1); }

    // ---------------- Phase 2: masked exact softmax; one wave per row
    {
        const int row = w;              // 8 rows, 8 waves
        const int c   = l;
        bf16_t* srow = sc + (size_t)row * PITCH;

        float m = -3.4e38f;
        #pragma unroll
        for (int j = 0; j < 4; ++j) {
            bf16x8 x = *(const bf16x8*)(srow + (c + j * 64) * 8);
            unsigned int bits = mby[j];
            #pragma unroll
            for (int u = 0; u < 8; ++u) {
                float s = (float)x[u] + (((bits >> u) & 1u) ? 0.f : NEGINF);
                m = fmaxf(m, s);
            }
        }
        #pragma unroll
        for (int off = 32; off; off >>= 1) m = fmaxf(m, __shfl_xor(m, off));

        float sum = 0.f;
        #pragma unroll
        for (int j = 0; j < 4; ++j) {
            bf16x8 x = *(bf16x8*)(srow + (c + j * 64) * 8);
            unsigned int bits = mby[j];
            bf16x8 e;
            #pragma unroll
            for (int u = 0; u < 8; ++u) {
                float s  = (float)x[u] + (((bits >> u) & 1u) ? 0.f : NEGINF);
                float ev = __expf(s - m);
                sum += ev;
                e[u] = (bf16_t)ev;
            }
            *(bf16x8*)(srow + (c + j * 64) * 8) = e;
        }
        #pragma unroll
        for (int off = 32; off; off >>= 1) sum += __shfl_xor(sum, off);
        if (c == 0) inv_l[row] = 1.f / sum;
    }
    __syncthreads();

    // ---------------- Phase 3: fused PV MFMA + attn write.
    // Chunk ks (32 k-cols, all 8 rows) is written by wave (ks & 7): one
    // ds_read_b64 + one NT f32x4 store per owned iteration, spread evenly.
    const float il8 = inv_l[l >> 3];
    const int   wrow_ = l >> 3;
    const int   wc4_  = (l & 7) * 4;

    if (WS) {
        auto pvstep = [&](int ks, bf16x8& VB) {
            bf16x8 a0 = *(const bf16x8*)(sc + (size_t)q8 * PITCH + ks * 32 + lg * 8);
            acc3 = __builtin_amdgcn_mfma_f32_16x16x32_bf16(a0, VB, acc3, 0, 0, 0);
            if ((ks & 7) == w) {
                bf16x4 x = *(const bf16x4*)(sc + (size_t)wrow_ * PITCH + ks * 32 + wc4_);
                f32x4 o;
                o[0] = (float)x[0] * il8; o[1] = (float)x[1] * il8;
                o[2] = (float)x[2] * il8; o[3] = (float)x[3] * il8;
                __builtin_nontemporal_store(o, (f32x4*)(attnp + (size_t)wrow_ * L_ + ks * 32 + wc4_));
            }
        };
        #pragma unroll 1
        for (int ks = 0; ks < 64; ks += 4) {
            pvstep(ks, VB0);     if (ks + 4 < 64) loadVT(ks + 4, VB0);
            pvstep(ks + 1, VB1); if (ks + 5 < 64) loadVT(ks + 5, VB1);
            pvstep(ks + 2, VB2); if (ks + 6 < 64) loadVT(ks + 6, VB2);
            pvstep(ks + 3, VB3); if (ks + 7 < 64) loadVT(ks + 7, VB3);
        }
    } else {
        #pragma unroll 1
        for (int i = 0; i < 8; ++i) {
            int f  = tid + i * 512;
            int rw = f >> 9;
            int c4 = f & 511;
            bf16x4 x = *(const bf16x4*)(sc + (size_t)rw * PITCH + c4 * 4);
            float il = inv_l[rw];
            f32x4 o;
            o[0] = (float)x[0] * il; o[1] = (float)x[1] * il;
            o[2] = (float)x[2] * il; o[3] = (float)x[3] * il;
            __builtin_nontemporal_store(o, (f32x4*)(attnp + (size_t)rw * L_ + c4 * 4));
        }
        #pragma unroll 1
        for (int ks = 0; ks < 64; ks += 2) {
            bf16x8 bb;
            #pragma unroll
            for (int u = 0; u < 8; ++u) bb[u] = (bf16_t)vr0[u];
            if (ks + 2 < 64) loadVg(ks + 2, vr0);
            bf16x8 a0 = *(const bf16x8*)(sc + (size_t)q8 * PITCH + ks * 32 + lg * 8);
            acc3 = __builtin_amdgcn_mfma_f32_16x16x32_bf16(a0, bb, acc3, 0, 0, 0);

            bf16x8 bb1;
            #pragma unroll
            for (int u = 0; u < 8; ++u) bb1[u] = (bf16_t)vr1[u];
            if (ks + 3 < 64) loadVg(ks + 3, vr1);
            bf16x8 a1 = *(const bf16x8*)(sc + (size_t)q8 * PITCH + (ks + 1) * 32 + lg * 8);
            acc3 = __builtin_amdgcn_mfma_f32_16x16x32_bf16(a1, bb1, acc3, 0, 0, 0);
        }
    }

    // ---------------- Epilogue: out = acc * inv_l
    {
        const int dcol = d0 + li;
        if (lg < 2) {
            #pragma unroll
            for (int r = 0; r < 4; ++r) {
                int row = lg * 4 + r;   // 0..7
                __builtin_nontemporal_store(acc3[r] * inv_l[row],
                                            outp + (size_t)row * D_ + dcol);
            }
        }
    }
}

extern "C" void kernel_launch(void* const* d_in, const int* in_sizes, int n_in,
                              void* d_out, int out_size, void* d_ws, size_t ws_size,
                              hipStream_t stream) {
    const float* q    = (const float*)d_in[0];
    const float* k    = (const float*)d_in[1];
    const float* v    = (const float*)d_in[2];
    const int*   mask = (const int*)d_in[3];

    float* out  = (float*)d_out;
    float* attn = out + (size_t)B_ * L_ * D_;

    const size_t VT_BYTES = (size_t)B_ * D_ * L_ * 2;   // 8 MB
    const size_t KB_BYTES = (size_t)B_ * L_ * D_ * 2;   // 8 MB
    const bool ws_ok = ws_size >= VT_BYTES + KB_BYTES;
    bf16_t* vt = (bf16_t*)d_ws;
    bf16_t* kb = (bf16_t*)((char*)d_ws + VT_BYTES);

    if (ws_ok) {
        hipLaunchKernelGGL(prep_kernel, dim3(512), dim3(256), 0, stream, k, v, kb, vt);
        hipLaunchKernelGGL(sdpa_kernel<true>, dim3(4096), dim3(512), 0, stream,
                           q, k, v, mask, kb, vt, out, attn);
    } else {
        hipLaunchKernelGGL(sdpa_kernel<false>, dim3(4096), dim3(512), 0, stream,
                           q, k, v, mask, kb, vt, out, attn);
    }
}

// Round 6
// 405.944 us; speedup vs baseline: 1.7902x; 1.3005x over previous
//
#include <hip/hip_runtime.h>

typedef __bf16 bf16_t;
typedef __bf16 bf16x8 __attribute__((ext_vector_type(8)));
typedef __bf16 bf16x4 __attribute__((ext_vector_type(4)));
typedef float  f32x4  __attribute__((ext_vector_type(4)));
typedef int    i32x4  __attribute__((ext_vector_type(4)));

#define B_      16
#define L_      2048
#define D_      128
#define QTB     128              // q rows per block = 8 waves x 16
#define NEGINF  (-1.0e9f)
#define SCALE   0.08838834764831845f   // 1/sqrt(128)

// ---------------------------------------------------------------------------
// Prep kernel: blocks 0..255  : V fp32 [B][L][D] -> bf16 VT [B][D][L]
//              blocks 256..511: K fp32 -> bf16 row-major
// ---------------------------------------------------------------------------
__global__ __launch_bounds__(256) void prep_kernel(
    const float* __restrict__ k, const float* __restrict__ v,
    bf16_t* __restrict__ kb, bf16_t* __restrict__ vt)
{
    __shared__ bf16_t tile[128 * 144];
    const int tid = threadIdx.x;
    const int bid = (int)blockIdx.x;

    if (bid < 256) {
        const int b  = bid >> 4;
        const int l0 = (bid & 15) * 128;
        #pragma unroll
        for (int it = 0; it < 16; ++it) {
            int idx = tid + it * 256;
            int row = idx >> 5;
            int dc4 = idx & 31;
            f32x4 x = __builtin_nontemporal_load(
                (const f32x4*)(v + ((size_t)b * L_ + l0 + row) * (size_t)D_ + dc4 * 4));
            #pragma unroll
            for (int i = 0; i < 4; ++i) tile[(dc4 * 4 + i) * 144 + row] = (bf16_t)x[i];
        }
        __syncthreads();
        #pragma unroll
        for (int it = 0; it < 8; ++it) {
            int idx = tid + it * 256;
            int d   = idx >> 4;
            int lc  = idx & 15;
            bf16x8 vec = *(const bf16x8*)&tile[d * 144 + lc * 8];
            *(bf16x8*)(vt + ((size_t)b * D_ + d) * (size_t)L_ + l0 + lc * 8) = vec;
        }
    } else {
        const int idx0 = (bid - 256) * 256 + tid;
        #pragma unroll
        for (int c = 0; c < 16; ++c) {
            int idx = idx0 + c * 65536;
            f32x4 x = __builtin_nontemporal_load((const f32x4*)(k + (size_t)idx * 4));
            bf16x4 o;
            #pragma unroll
            for (int i = 0; i < 4; ++i) o[i] = (bf16_t)x[i];
            *(bf16x4*)(kb + (size_t)idx * 4) = o;
        }
    }
}

// ---------------------------------------------------------------------------
// Main kernel: 256 blocks (1/CU), 8 waves, 128 q-rows/block, NO barriers.
// Each wave: 16 q-rows, two passes over all 2048 k.
//  Pass 1: QK^T (K A-frags from L2-resident kb) + online masked max/sum;
//          mask streamed from HBM, packed 1-bit into per-wave LDS.
//  Pass 2: recompute QK^T, p=exp(s-m) fp32 -> NT attn write; p->bf16 via
//          per-wave LDS bounce -> A-frag; 8 PV MFMAs/chunk from VT (L2).
// ---------------------------------------------------------------------------
template <bool WS>
__global__ __launch_bounds__(512) void sdpa_kernel(
    const float* __restrict__ q, const float* __restrict__ k,
    const float* __restrict__ v, const int* __restrict__ mask,
    const bf16_t* __restrict__ kb, const bf16_t* __restrict__ vt,
    float* __restrict__ out, float* __restrict__ attn)
{
    __shared__ unsigned mlds[8 * 1024];     // 32 KB: packed mask bits, per-wave
    __shared__ bf16_t   plds[8][16][40];    // 10 KB: per-wave P bounce tile

    const int tid = threadIdx.x;
    const int w   = tid >> 6;
    const int l   = tid & 63;
    const int li  = l & 15;
    const int lg  = l >> 4;

    // XCD-chunked bijective swizzle (256 % 8 == 0): 2 batches per XCD
    const int bid  = (int)blockIdx.x;
    const int bid2 = (bid & 7) * 32 + (bid >> 3);
    const int b    = bid2 >> 4;
    const int qt   = bid2 & 15;
    const int qbase = qt * QTB;

    const size_t bq   = (size_t)b * L_;
    const int    qrow = qbase + w * 16 + li;       // this lane's q row

    const float*  qp   = q  + (bq + qbase) * (size_t)D_;
    const bf16_t* kbp  = kb + bq * (size_t)D_;
    const float*  kp   = k  + bq * (size_t)D_;
    const bf16_t* vtp  = vt + (size_t)b * D_ * (size_t)L_;
    const float*  vp   = v  + bq * (size_t)D_;
    const int*    mrow = mask + (bq + qrow) * (size_t)L_;
    float* attnrow = attn + (bq + qrow) * (size_t)L_;
    float* outp    = out  + (bq + qbase) * (size_t)D_;

    // ---------------- Q B-fragments (pre-scaled by 1/temper)
    bf16x8 aq[4];
    #pragma unroll
    for (int ds = 0; ds < 4; ++ds) {
        const float* p = qp + (size_t)(w * 16 + li) * D_ + ds * 32 + lg * 8;
        f32x4 x0 = *(const f32x4*)p;
        f32x4 x1 = *(const f32x4*)(p + 4);
        bf16x8 a;
        #pragma unroll
        for (int u = 0; u < 4; ++u) {
            a[u]     = (bf16_t)(x0[u] * SCALE);
            a[4 + u] = (bf16_t)(x1[u] * SCALE);
        }
        aq[ds] = a;
    }

    // K 16-row tile -> A-frag (lane li = k-row, elems = d)
    bf16x8 KA[4], KB[4];
    auto loadK16 = [&](int t, bf16x8* dst) {
        if (WS) {
            const bf16_t* p = kbp + (size_t)(t * 16 + li) * D_;
            #pragma unroll
            for (int ds = 0; ds < 4; ++ds) dst[ds] = *(const bf16x8*)(p + ds * 32 + lg * 8);
        } else {
            const float* p = kp + (size_t)(t * 16 + li) * D_;
            #pragma unroll
            for (int ds = 0; ds < 4; ++ds) {
                f32x4 x0 = *(const f32x4*)(p + ds * 32 + lg * 8);
                f32x4 x1 = *(const f32x4*)(p + ds * 32 + lg * 8 + 4);
                bf16x8 a;
                #pragma unroll
                for (int u = 0; u < 4; ++u) { a[u] = (bf16_t)x0[u]; a[4+u] = (bf16_t)x1[u]; }
                dst[ds] = a;
            }
        }
    };

    // ================= PASS 1: online masked max/sum =================
    float m_run = -3.4e38f, l_run = 0.f;
    i32x4 mA[2], mB[2];
    auto loadM = [&](int c, int s) {
        mA[s] = __builtin_nontemporal_load((const i32x4*)(mrow + c * 32 + lg * 4));
        mB[s] = __builtin_nontemporal_load((const i32x4*)(mrow + c * 32 + 16 + lg * 4));
    };

    loadK16(0, KA); loadK16(1, KB);
    loadM(0, 0); loadM(1, 1);

    #pragma unroll 1
    for (int c4 = 0; c4 < 16; ++c4) {
        unsigned mword = 0;
        #pragma unroll
        for (int sub = 0; sub < 4; ++sub) {
            const int c = c4 * 4 + sub;
            f32x4 a0 = {0.f,0.f,0.f,0.f}, a1 = {0.f,0.f,0.f,0.f};
            #pragma unroll
            for (int ds = 0; ds < 4; ++ds)
                a0 = __builtin_amdgcn_mfma_f32_16x16x32_bf16(KA[ds], aq[ds], a0, 0, 0, 0);
            if (c < 63) loadK16(2 * c + 2, KA);
            #pragma unroll
            for (int ds = 0; ds < 4; ++ds)
                a1 = __builtin_amdgcn_mfma_f32_16x16x32_bf16(KB[ds], aq[ds], a1, 0, 0, 0);
            if (c < 63) loadK16(2 * c + 3, KB);

            const int s = sub & 1;
            i32x4 va = mA[s], vb_ = mB[s];
            unsigned byte =
                (va[0]  != 0 ?   1u : 0u) | (va[1]  != 0 ?   2u : 0u) |
                (va[2]  != 0 ?   4u : 0u) | (va[3]  != 0 ?   8u : 0u) |
                (vb_[0] != 0 ?  16u : 0u) | (vb_[1] != 0 ?  32u : 0u) |
                (vb_[2] != 0 ?  64u : 0u) | (vb_[3] != 0 ? 128u : 0u);
            if (c + 2 < 64) loadM(c + 2, s);

            float s0[4], s1[4];
            #pragma unroll
            for (int r = 0; r < 4; ++r) {
                s0[r] = a0[r] + (((byte >> r)       & 1u) ? 0.f : NEGINF);
                s1[r] = a1[r] + (((byte >> (4 + r)) & 1u) ? 0.f : NEGINF);
            }
            float mx = fmaxf(fmaxf(fmaxf(s0[0], s0[1]), fmaxf(s0[2], s0[3])),
                             fmaxf(fmaxf(s1[0], s1[1]), fmaxf(s1[2], s1[3])));
            mx = fmaxf(mx, m_run);
            float acc = 0.f;
            #pragma unroll
            for (int r = 0; r < 4; ++r)
                acc += __expf(s0[r] - mx) + __expf(s1[r] - mx);
            l_run = l_run * __expf(m_run - mx) + acc;
            m_run = mx;
            mword |= byte << (sub * 8);
        }
        mlds[w * 1024 + c4 * 64 + l] = mword;     // wave-private, no barrier
    }

    // merge m/sum across the 4 lane-groups (lanes li, li+16, li+32, li+48)
    #pragma unroll
    for (int off = 16; off < 64; off <<= 1) {
        float mo = __shfl_xor(m_run, off);
        float lo = __shfl_xor(l_run, off);
        float mn = fmaxf(m_run, mo);
        l_run = l_run * __expf(m_run - mn) + lo * __expf(mo - mn);
        m_run = mn;
    }
    const float inv_l = 1.f / l_run;

    // ================= PASS 2: recompute + attn write + PV =================
    f32x4 pv[8];
    #pragma unroll
    for (int dt = 0; dt < 8; ++dt) pv[dt] = {0.f,0.f,0.f,0.f};

    loadK16(0, KA); loadK16(1, KB);

    #pragma unroll 1
    for (int c4 = 0; c4 < 16; ++c4) {
        unsigned mword = mlds[w * 1024 + c4 * 64 + l];
        #pragma unroll
        for (int sub = 0; sub < 4; ++sub) {
            const int c = c4 * 4 + sub;

            // V B-frags for this chunk (issued early; consumed at chunk end)
            bf16x8 vb[8];
            if (WS) {
                #pragma unroll
                for (int dt = 0; dt < 8; ++dt)
                    vb[dt] = *(const bf16x8*)(vtp + (size_t)(dt * 16 + li) * L_ + c * 32 + lg * 8);
            } else {
                #pragma unroll
                for (int dt = 0; dt < 8; ++dt) {
                    bf16x8 a;
                    #pragma unroll
                    for (int u = 0; u < 8; ++u)
                        a[u] = (bf16_t)vp[(size_t)(c * 32 + lg * 8 + u) * D_ + dt * 16 + li];
                    vb[dt] = a;
                }
            }

            f32x4 a0 = {0.f,0.f,0.f,0.f}, a1 = {0.f,0.f,0.f,0.f};
            #pragma unroll
            for (int ds = 0; ds < 4; ++ds)
                a0 = __builtin_amdgcn_mfma_f32_16x16x32_bf16(KA[ds], aq[ds], a0, 0, 0, 0);
            if (c < 63) loadK16(2 * c + 2, KA);
            #pragma unroll
            for (int ds = 0; ds < 4; ++ds)
                a1 = __builtin_amdgcn_mfma_f32_16x16x32_bf16(KB[ds], aq[ds], a1, 0, 0, 0);
            if (c < 63) loadK16(2 * c + 3, KB);

            const unsigned byte = (mword >> (sub * 8)) & 0xffu;
            f32x4 o0, o1; bf16x4 pb0, pb1;
            #pragma unroll
            for (int r = 0; r < 4; ++r) {
                float sa = a0[r] + (((byte >> r)       & 1u) ? 0.f : NEGINF);
                float sb = a1[r] + (((byte >> (4 + r)) & 1u) ? 0.f : NEGINF);
                float p0 = __expf(sa - m_run);
                float p1 = __expf(sb - m_run);
                o0[r] = p0 * inv_l;  o1[r] = p1 * inv_l;
                pb0[r] = (bf16_t)p0; pb1[r] = (bf16_t)p1;
            }
            // attn: fp32, 64B segment per row, non-temporal
            __builtin_nontemporal_store(o0, (f32x4*)(attnrow + c * 32 + lg * 4));
            __builtin_nontemporal_store(o1, (f32x4*)(attnrow + c * 32 + 16 + lg * 4));

            // C-layout -> A-frag via per-wave LDS bounce (same-wave, waitcnt only)
            *(bf16x4*)&plds[w][li][lg * 4]      = pb0;
            *(bf16x4*)&plds[w][li][16 + lg * 4] = pb1;
            bf16x8 pa = *(const bf16x8*)&plds[w][li][lg * 8];

            #pragma unroll
            for (int dt = 0; dt < 8; ++dt)
                pv[dt] = __builtin_amdgcn_mfma_f32_16x16x32_bf16(pa, vb[dt], pv[dt], 0, 0, 0);
        }
    }

    // ---------------- Epilogue: out[q][d] = pv * inv_l[q]
    #pragma unroll
    for (int r = 0; r < 4; ++r) {
        const float il = __shfl(inv_l, lg * 4 + r);    // lane (lg*4+r) holds q=lg*4+r
        float* orow = outp + (size_t)(w * 16 + lg * 4 + r) * D_ + li;
        #pragma unroll
        for (int dt = 0; dt < 8; ++dt)
            __builtin_nontemporal_store(pv[dt][r] * il, orow + dt * 16);
    }
}

extern "C" void kernel_launch(void* const* d_in, const int* in_sizes, int n_in,
                              void* d_out, int out_size, void* d_ws, size_t ws_size,
                              hipStream_t stream) {
    const float* q    = (const float*)d_in[0];
    const float* k    = (const float*)d_in[1];
    const float* v    = (const float*)d_in[2];
    const int*   mask = (const int*)d_in[3];

    float* out  = (float*)d_out;
    float* attn = out + (size_t)B_ * L_ * D_;

    const size_t VT_BYTES = (size_t)B_ * D_ * L_ * 2;   // 8 MB
    const size_t KB_BYTES = (size_t)B_ * L_ * D_ * 2;   // 8 MB
    const bool ws_ok = ws_size >= VT_BYTES + KB_BYTES;
    bf16_t* vt = (bf16_t*)d_ws;
    bf16_t* kb = (bf16_t*)((char*)d_ws + VT_BYTES);

    if (ws_ok) {
        hipLaunchKernelGGL(prep_kernel, dim3(512), dim3(256), 0, stream, k, v, kb, vt);
        hipLaunchKernelGGL(sdpa_kernel<true>, dim3(256), dim3(512), 0, stream,
                           q, k, v, mask, kb, vt, out, attn);
    } else {
        hipLaunchKernelGGL(sdpa_kernel<false>, dim3(256), dim3(512), 0, stream,
                           q, k, v, mask, kb, vt, out, attn);
    }
}